// Round 1
// baseline (54836.884 us; speedup 1.0000x reference)
//
#include <hip/hip_runtime.h>

// ---- problem constants ----
#define BATCH 2048
#define TT    128
#define FF    64
#define HH    512
#define GG    2048   // 4H
#define K1    576    // H + F   (layer1: [h1 || x_t])
#define K2    1024   // H + H   (layer2: [h2 || h1_t])
#define KB1   72     // K1/8
#define KB2   128    // K2/8

using f16x8 = __attribute__((ext_vector_type(8))) _Float16;
using f32x4 = __attribute__((ext_vector_type(4))) float;

// ---------------------------------------------------------------------------
// Repack [U;W] (fp32, row-major [K][2048]) into MFMA-fragment-native fp16:
//   element (ct, kb, c, j) at idx = ((ct*K8 + kb)*16 + c)*8 + j
//   holds B[k = kb*8+j][col = (c&3)*512 + ct*4 + (c>>2)]
// i.e. tile ct's 16 columns = 4 h-units x {i,f,cin,o} interleaved, and each
// lane's 8 k-elements are contiguous (16B). Also permutes the bias.
// ---------------------------------------------------------------------------
__global__ void pack_weights(const float* __restrict__ U, const float* __restrict__ W,
                             const float* __restrict__ bias, int K, int Kh,
                             _Float16* __restrict__ Bp, float* __restrict__ pb)
{
    int K8 = K >> 3;
    int total = K * GG;
    for (int idx = blockIdx.x * blockDim.x + threadIdx.x; idx < total + GG;
         idx += gridDim.x * blockDim.x) {
        if (idx < total) {
            int j = idx & 7, c = (idx >> 3) & 15, rem = idx >> 7;
            int kb = rem % K8, ct = rem / K8;
            int k = kb * 8 + j;
            int col = (c & 3) * HH + ct * 4 + (c >> 2);
            float v = (k < Kh) ? U[k * GG + col] : W[(k - Kh) * GG + col];
            Bp[idx] = (_Float16)v;
        } else {
            int p = idx - total, ct = p >> 4, c = p & 15;
            pb[p] = bias[(c & 3) * HH + ct * 4 + (c >> 2)];
        }
    }
}

// ---------------------------------------------------------------------------
// Per-wave GEMM: 16 batch rows x 2048 gate cols, K = NKC*32.
// wave w owns col-tiles [w*16, w*16+16), processed 4 at a time (4 indep
// MFMA chains for ILP). A operand from LDS (ds_read_b128), B direct from
// global (coalesced 1KB/wave dwordx4 loads, L2-served, zero reuse in block).
// ---------------------------------------------------------------------------
template <int NKC, int KB>
__device__ __forceinline__ void do_gemm(const _Float16* __restrict__ Bp,
                                        const _Float16* __restrict__ aptr,
                                        int wave, int lane, f32x4 acc[16])
{
    const int row = lane & 15, kq = lane >> 4;
#pragma unroll
    for (int cg = 0; cg < 4; ++cg) {
        const int ct0 = wave * 16 + cg * 4;
        const _Float16* b0p = Bp + ((ct0 * KB + kq) * 16 + row) * 8;
        f32x4 a0{0.f, 0.f, 0.f, 0.f}, a1 = a0, a2 = a0, a3 = a0;
        for (int kc = 0; kc < NKC; ++kc) {
            f16x8 av = *(const f16x8*)(aptr + kc * 32);
            const _Float16* bp = b0p + kc * 512;          // kb advances 4 -> 4*16*8
            f16x8 b0 = *(const f16x8*)(bp);
            f16x8 b1 = *(const f16x8*)(bp + KB * 128);    // next col-tile
            f16x8 b2 = *(const f16x8*)(bp + 2 * KB * 128);
            f16x8 b3 = *(const f16x8*)(bp + 3 * KB * 128);
            a0 = __builtin_amdgcn_mfma_f32_16x16x32_f16(av, b0, a0, 0, 0, 0);
            a1 = __builtin_amdgcn_mfma_f32_16x16x32_f16(av, b1, a1, 0, 0, 0);
            a2 = __builtin_amdgcn_mfma_f32_16x16x32_f16(av, b2, a2, 0, 0, 0);
            a3 = __builtin_amdgcn_mfma_f32_16x16x32_f16(av, b3, a3, 0, 0, 0);
        }
        acc[cg * 4 + 0] = a0; acc[cg * 4 + 1] = a1;
        acc[cg * 4 + 2] = a2; acc[cg * 4 + 3] = a3;
    }
}

// ---------------------------------------------------------------------------
// Gate epilogue. C/D layout (verified): col = lane&15, row = (lane>>4)*4+reg.
// Tile cols are unit-major gate-interleaved, so lanes (l&~3)+{0,1,2,3} hold
// {i,f,cin,o} of one h-unit for the same 4 rows -> 4 bpermutes gather all
// gates; gate math in fp32; gate-0 lanes commit c (fp32 LDS) and h (fp16 LDS).
// ---------------------------------------------------------------------------
__device__ __forceinline__ void lstm_epilogue(const f32x4 acc[16], int wave, int lane,
                                              const float* __restrict__ pb,
                                              float* __restrict__ cs, int csLd,
                                              _Float16* __restrict__ h0, int h0Ld,
                                              _Float16* __restrict__ h1, int h1Ld)
{
    const int c = lane & 15, gsel = c & 3, ul = c >> 2;
    const int row0 = (lane >> 4) * 4;
    const int src = lane & ~3;
#pragma unroll
    for (int ci = 0; ci < 16; ++ci) {
        const int ct = wave * 16 + ci;
        const int Uc = ct * 4 + ul;
        const float bias = pb[ct * 16 + c];
#pragma unroll
        for (int j = 0; j < 4; ++j) {
            float v = acc[ci][j] + bias;
            float vi = __shfl(v, src + 0);
            float vf = __shfl(v, src + 1);
            float vc = __shfl(v, src + 2);
            float vo = __shfl(v, src + 3);
            float ig = 1.f / (1.f + __expf(-vi));
            float fg = 1.f / (1.f + __expf(-vf));
            float og = 1.f / (1.f + __expf(-vo));
            float cin = vc > 0.f ? vc : 0.f;
            int R = row0 + j;
            float cprev = cs[R * csLd + Uc];
            float cnew = fg * cprev + ig * cin;
            float hnew = og * (cnew > 0.f ? cnew : 0.f);
            if (gsel == 0) {
                cs[R * csLd + Uc] = cnew;
                _Float16 hh = (_Float16)hnew;
                h0[R * h0Ld + Uc] = hh;
                if (h1) h1[R * h1Ld + Uc] = hh;
            }
        }
    }
}

// ---------------------------------------------------------------------------
// Persistent fused 2-layer LSTM. 128 blocks x 512 threads (8 waves); block
// owns 16 batch rows for all 128 timesteps -> zero inter-block sync.
// LDS: A1=[h1||x_t] (K1, +8 pad), A2=[h2||h1] (K2, +8 pad), c1,c2 fp32.
// Row strides chosen so ds_read_b128 aliasing is 2-way (free).
// ---------------------------------------------------------------------------
__global__ __launch_bounds__(512, 2) void lstm_fused(
    const float* __restrict__ x,
    const _Float16* __restrict__ Bp1, const float* __restrict__ pb1,
    const _Float16* __restrict__ Bp2, const float* __restrict__ pb2,
    const float* __restrict__ Wd, const float* __restrict__ bd,
    float* __restrict__ out)
{
    __shared__ _Float16 A1[16][584];    // 512 h1 | 64 x | 8 pad
    __shared__ _Float16 A2[16][1032];   // 512 h2 | 512 h1 | 8 pad
    __shared__ float    c1s[16][516];
    __shared__ float    c2s[16][516];

    const int tid = threadIdx.x;
    const int wave = tid >> 6, lane = tid & 63;
    const int r0 = blockIdx.x * 16;

    for (int i = tid; i < 16 * 584; i += 512)  (&A1[0][0])[i] = (_Float16)0.f;
    for (int i = tid; i < 16 * 1032; i += 512) (&A2[0][0])[i] = (_Float16)0.f;
    for (int i = tid; i < 16 * 516; i += 512) { (&c1s[0][0])[i] = 0.f; (&c2s[0][0])[i] = 0.f; }
    __syncthreads();

    const int row = lane & 15, kq = lane >> 4;
    const _Float16* a1ptr = &A1[row][kq * 8];
    const _Float16* a2ptr = &A2[row][kq * 8];

    for (int t = 0; t < TT; ++t) {
        { // stage x_t -> A1[:,512:576] (fp32 -> fp16), coalesced 128B rows
            int r = tid >> 5, f = tid & 31;
            const float* xr = x + ((r0 + r) * TT + t) * FF;
            A1[r][512 + f]      = (_Float16)xr[f];
            A1[r][512 + 32 + f] = (_Float16)xr[32 + f];
        }
        __syncthreads();

        { // ---- layer 1: g = [h1||x_t] @ [U1;W1] + b1 ----
            f32x4 acc[16];
            do_gemm<18, KB1>(Bp1, a1ptr, wave, lane, acc);
            __syncthreads();  // all A1 reads done before h1 overwrite
            lstm_epilogue(acc, wave, lane, pb1,
                          &c1s[0][0], 516,
                          &A1[0][0], 584,            // h1 -> next layer1 A
                          &A2[0][0] + 512, 1032);    // h1 -> layer2 input half
            __syncthreads();
        }
        { // ---- layer 2: g = [h2||h1_t] @ [U2;W2] + b2 ----
            f32x4 acc[16];
            do_gemm<32, KB2>(Bp2, a2ptr, wave, lane, acc);
            __syncthreads();
            lstm_epilogue(acc, wave, lane, pb2,
                          &c2s[0][0], 516,
                          &A2[0][0], 1032,           // h2 -> recurrent half
                          (_Float16*)nullptr, 0);
            __syncthreads();
        }
    }

    { // dense head: out = h2 @ Wd + bd (fp32), 32 threads per row
        int r = tid >> 5, sg = tid & 31;
        float s = 0.f;
        for (int k = sg; k < HH; k += 32) s += (float)A2[r][k] * Wd[k];
        for (int off = 16; off > 0; off >>= 1) s += __shfl_down(s, off, 32);
        if (sg == 0) out[r0 + r] = s + bd[0];
    }
}

extern "C" void kernel_launch(void* const* d_in, const int* in_sizes, int n_in,
                              void* d_out, int out_size, void* d_ws, size_t ws_size,
                              hipStream_t stream)
{
    const float* x  = (const float*)d_in[0];
    const float* W1 = (const float*)d_in[1];
    const float* U1 = (const float*)d_in[2];
    const float* b1 = (const float*)d_in[3];
    const float* W2 = (const float*)d_in[4];
    const float* U2 = (const float*)d_in[5];
    const float* b2 = (const float*)d_in[6];
    const float* Wd = (const float*)d_in[7];
    const float* bd = (const float*)d_in[8];
    float* out = (float*)d_out;

    char* ws = (char*)d_ws;
    _Float16* Bp1 = (_Float16*)ws;                                   // K1*G fp16
    _Float16* Bp2 = (_Float16*)(ws + (size_t)K1 * GG * 2);           // K2*G fp16
    float*    pb1 = (float*)(ws + (size_t)(K1 + K2) * GG * 2);       // G fp32
    float*    pb2 = pb1 + GG;

    pack_weights<<<512, 256, 0, stream>>>(U1, W1, b1, K1, HH, Bp1, pb1);
    pack_weights<<<512, 256, 0, stream>>>(U2, W2, b2, K2, HH, Bp2, pb2);
    lstm_fused<<<128, 512, 0, stream>>>(x, Bp1, pb1, Bp2, pb2, Wd, bd, out);
}

// Round 2
// 8285.776 us; speedup vs baseline: 6.6182x; 6.6182x over previous
//
#include <hip/hip_runtime.h>

#define TT   128
#define FF   64
#define HH   512
#define GG   2048    // 4H
#define K1   576
#define K2   1024
#define KB1  72      // K1/8
#define KB2  128     // K2/8
#define NBLK 256

using f16x8 = __attribute__((ext_vector_type(8))) _Float16;
using f32x4 = __attribute__((ext_vector_type(4))) float;

// ---------------------------------------------------------------------------
// Repack [U;W] (fp32 [K][2048]) into MFMA-fragment-native fp16 (unchanged,
// validated in round 1): element (ct,kb,c,j) at ((ct*K8+kb)*16+c)*8+j holds
// B[k=kb*8+j][col=(c&3)*512 + ct*4 + (c>>2)]. Bias permuted the same way.
// ---------------------------------------------------------------------------
__global__ void pack_weights(const float* __restrict__ U, const float* __restrict__ W,
                             const float* __restrict__ bias, int K, int Kh,
                             _Float16* __restrict__ Bp, float* __restrict__ pb)
{
    int K8 = K >> 3;
    int total = K * GG;
    for (int idx = blockIdx.x * blockDim.x + threadIdx.x; idx < total + GG;
         idx += gridDim.x * blockDim.x) {
        if (idx < total) {
            int j = idx & 7, c = (idx >> 3) & 15, rem = idx >> 7;
            int kb = rem % K8, ct = rem / K8;
            int k = kb * 8 + j;
            int col = (c & 3) * HH + ct * 4 + (c >> 2);
            float v = (k < Kh) ? U[k * GG + col] : W[(k - Kh) * GG + col];
            Bp[idx] = (_Float16)v;
        } else {
            int p = idx - total, ct = p >> 4, c = p & 15;
            pb[p] = bias[(c & 3) * HH + ct * 4 + (c >> 2)];
        }
    }
}

// ---------------------------------------------------------------------------
// Gate epilogue (validated round 1). C/D layout: col=lane&15, row=(lane>>4)*4+reg.
// Cols are unit-major gate-interleaved: lanes (l&~3)+{0,1,2,3} = {i,f,cin,o}.
// cs: block-local cell state [128][32] fp32 in LDS. hdst: global h buffer
// (parity applied), gets fp16 h for this wave's 4 units.
// ---------------------------------------------------------------------------
__device__ __forceinline__ void lstm_epi(
    f32x4 acc, int lane, int wave, float bias,
    float* __restrict__ cs, _Float16* __restrict__ hdst,
    int lrow0, int grow0, int u0)
{
    const int c = lane & 15, gsel = c & 3, ul = c >> 2;
    const int srcl = lane & ~3;
    const int row0 = (lane >> 4) * 4;
    const int ublk = wave * 4 + ul;
#pragma unroll
    for (int j = 0; j < 4; ++j) {
        float v = acc[j] + bias;
        float vi = __shfl(v, srcl + 0);
        float vf = __shfl(v, srcl + 1);
        float vc = __shfl(v, srcl + 2);
        float vo = __shfl(v, srcl + 3);
        float ig = 1.f / (1.f + __expf(-vi));
        float fg = 1.f / (1.f + __expf(-vf));
        float og = 1.f / (1.f + __expf(-vo));
        float cin = vc > 0.f ? vc : 0.f;
        int R = lrow0 + row0 + j;
        float cprev = cs[R * 32 + ublk];
        float cnew = fg * cprev + ig * cin;
        float hnew = og * (cnew > 0.f ? cnew : 0.f);
        if (gsel == 0) {
            cs[R * 32 + ublk] = cnew;
            hdst[(size_t)(grow0 + row0 + j) * HH + u0 + ul] = (_Float16)hnew;
        }
    }
}

// ---------------------------------------------------------------------------
// Persistent 2-layer LSTM. 256 blocks (1/CU, forced by 101 KB LDS) x 8 waves.
// Block b: rowgroup rg=b>>4 (128 rows), colgroup cg=b&15; wave w owns col-tile
// ct=cg*8+w (units ct*4..ct*4+3) of BOTH layers, weights held in 200 VGPRs.
// Skewed schedule: superstep s runs L1@t=s and L2@t=s-1; ONE grid barrier per
// superstep (monotone counter, all blocks co-resident). h1/h2 exchanged via
// double-buffered global fp16 buffers. A-operands staged per 32-row quarter.
// ---------------------------------------------------------------------------
__global__ __launch_bounds__(512, 2) void lstm_persist(
    const float* __restrict__ x,
    const _Float16* __restrict__ Bp1, const float* __restrict__ pb1,
    const _Float16* __restrict__ Bp2, const float* __restrict__ pb2,
    const float* __restrict__ Wd, const float* __restrict__ bd,
    _Float16* __restrict__ h1b,   // [2][2048][512]
    _Float16* __restrict__ h2b,   // [2][2048][512]
    unsigned* __restrict__ bar,
    float* __restrict__ out)
{
    __shared__ _Float16 Q1[32][584];   // [h1 512 | x 64 | pad 8]  (odd 16B-granule stride)
    __shared__ _Float16 Q2[32][520];   // [h2 512 | pad 8]
    __shared__ float    c1s[128 * 32];
    __shared__ float    c2s[128 * 32];

    const int tid  = threadIdx.x;
    const int w    = tid >> 6, lane = tid & 63;
    const int b    = blockIdx.x;
    const int rg   = b >> 4, cg = b & 15;
    const int r0   = rg * 128;
    const int ct   = cg * 8 + w;
    const int u0   = ct * 4;
    const int arow = lane & 15, kq8 = (lane >> 4) * 8;

    for (int i = tid; i < 128 * 32; i += 512) { c1s[i] = 0.f; c2s[i] = 0.f; }

    // ---- load this wave's weight fragments into registers (one-time) ----
    f16x8 w1f[18], w2f[32];
    {
        const int row = lane & 15, kq = lane >> 4;
        const _Float16* p1 = Bp1 + ((size_t)(ct * KB1 + kq) * 16 + row) * 8;
#pragma unroll
        for (int kc = 0; kc < 18; ++kc) w1f[kc] = *(const f16x8*)(p1 + kc * 512);
        const _Float16* p2 = Bp2 + ((size_t)(ct * KB2 + kq) * 16 + row) * 8;
#pragma unroll
        for (int kc = 0; kc < 32; ++kc) w2f[kc] = *(const f16x8*)(p2 + kc * 512);
    }
    const float bias1 = pb1[ct * 16 + (lane & 15)];
    const float bias2 = pb2[ct * 16 + (lane & 15)];

    for (int s = 0; s <= TT; ++s) {
        const int pr1 = (s + 1) & 1;          // h1_{s-1}
        const int pw1 = s & 1;                // h1_s
        const int pr2 = s & 1;                // h2_{s-2}
        const int pw2 = (s + 1) & 1;          // h2_{s-1}
        _Float16* h1w = h1b + (size_t)pw1 * 2048 * HH;
        _Float16* h2w = h2b + (size_t)pw2 * 2048 * HH;

        for (int q = 0; q < 4; ++q) {
            const int gr0 = r0 + q * 32;

            { // stage h1_{s-1} quarter (always: L1 k0-15, L2 k16-31)
                const _Float16* src = h1b + ((size_t)pr1 * 2048 + gr0) * HH;
#pragma unroll
                for (int i = tid; i < 2048; i += 512) {
                    int row = i >> 6, ch = (i & 63) * 8;
                    *(f16x8*)&Q1[row][ch] = *(const f16x8*)(src + row * HH + ch);
                }
            }
            if (s < TT) { // stage x_s quarter (fp32 -> fp16)
                int row = tid >> 4, c4 = (tid & 15) * 4;
                const float* xs = x + ((size_t)(gr0 + row) * TT + s) * FF + c4;
                Q1[row][512 + c4 + 0] = (_Float16)xs[0];
                Q1[row][512 + c4 + 1] = (_Float16)xs[1];
                Q1[row][512 + c4 + 2] = (_Float16)xs[2];
                Q1[row][512 + c4 + 3] = (_Float16)xs[3];
            }
            if (s >= 1) { // stage h2_{s-2} quarter
                const _Float16* src = h2b + ((size_t)pr2 * 2048 + gr0) * HH;
#pragma unroll
                for (int i = tid; i < 2048; i += 512) {
                    int row = i >> 6, ch = (i & 63) * 8;
                    *(f16x8*)&Q2[row][ch] = *(const f16x8*)(src + row * HH + ch);
                }
            }
            __syncthreads();

            if (s < TT) { // ---- L1: h1_s for quarter rows ----
                f32x4 a0{0.f, 0.f, 0.f, 0.f}, a1 = a0;
#pragma unroll
                for (int kc = 0; kc < 18; ++kc) {
                    f16x8 v0 = *(const f16x8*)&Q1[arow][kc * 32 + kq8];
                    f16x8 v1 = *(const f16x8*)&Q1[16 + arow][kc * 32 + kq8];
                    a0 = __builtin_amdgcn_mfma_f32_16x16x32_f16(v0, w1f[kc], a0, 0, 0, 0);
                    a1 = __builtin_amdgcn_mfma_f32_16x16x32_f16(v1, w1f[kc], a1, 0, 0, 0);
                }
                lstm_epi(a0, lane, w, bias1, c1s, h1w, q * 32,      gr0,      u0);
                lstm_epi(a1, lane, w, bias1, c1s, h1w, q * 32 + 16, gr0 + 16, u0);
            }
            if (s >= 1) { // ---- L2: h2_{s-1} for quarter rows ----
                f32x4 a0{0.f, 0.f, 0.f, 0.f}, a1 = a0;
#pragma unroll
                for (int kc = 0; kc < 16; ++kc) {
                    f16x8 v0 = *(const f16x8*)&Q2[arow][kc * 32 + kq8];
                    f16x8 v1 = *(const f16x8*)&Q2[16 + arow][kc * 32 + kq8];
                    a0 = __builtin_amdgcn_mfma_f32_16x16x32_f16(v0, w2f[kc], a0, 0, 0, 0);
                    a1 = __builtin_amdgcn_mfma_f32_16x16x32_f16(v1, w2f[kc], a1, 0, 0, 0);
                }
#pragma unroll
                for (int kc = 0; kc < 16; ++kc) {
                    f16x8 v0 = *(const f16x8*)&Q1[arow][kc * 32 + kq8];
                    f16x8 v1 = *(const f16x8*)&Q1[16 + arow][kc * 32 + kq8];
                    a0 = __builtin_amdgcn_mfma_f32_16x16x32_f16(v0, w2f[16 + kc], a0, 0, 0, 0);
                    a1 = __builtin_amdgcn_mfma_f32_16x16x32_f16(v1, w2f[16 + kc], a1, 0, 0, 0);
                }
                lstm_epi(a0, lane, w, bias2, c2s, h2w, q * 32,      gr0,      u0);
                lstm_epi(a1, lane, w, bias2, c2s, h2w, q * 32 + 16, gr0 + 16, u0);
            }
            __syncthreads();
        }

        // ---- grid barrier (monotone counter; all 256 blocks co-resident) ----
        if (tid == 0) {
            __threadfence();
            __hip_atomic_fetch_add(bar, 1u, __ATOMIC_ACQ_REL, __HIP_MEMORY_SCOPE_AGENT);
            const unsigned target = (unsigned)NBLK * (unsigned)(s + 1);
            while (__hip_atomic_load(bar, __ATOMIC_ACQUIRE, __HIP_MEMORY_SCOPE_AGENT) < target)
                __builtin_amdgcn_s_sleep(4);
            __threadfence();
        }
        __syncthreads();
    }

    // ---- dense head: out = h2_127 @ Wd + bd (cg==0 blocks only) ----
    if (cg == 0) {
        const _Float16* hf = h2b + (size_t)((TT - 1) & 1) * 2048 * HH;
        int r = tid >> 2, part = tid & 3;
        const _Float16* hr = hf + (size_t)(r0 + r) * HH + part * 128;
        const float* wd = Wd + part * 128;
        float ssum = 0.f;
        for (int u = 0; u < 128; ++u) ssum += (float)hr[u] * wd[u];
        ssum += __shfl_xor(ssum, 1);
        ssum += __shfl_xor(ssum, 2);
        if (part == 0) out[r0 + r] = ssum + bd[0];
    }
}

extern "C" void kernel_launch(void* const* d_in, const int* in_sizes, int n_in,
                              void* d_out, int out_size, void* d_ws, size_t ws_size,
                              hipStream_t stream)
{
    const float* x  = (const float*)d_in[0];
    const float* W1 = (const float*)d_in[1];
    const float* U1 = (const float*)d_in[2];
    const float* b1 = (const float*)d_in[3];
    const float* W2 = (const float*)d_in[4];
    const float* U2 = (const float*)d_in[5];
    const float* b2 = (const float*)d_in[6];
    const float* Wd = (const float*)d_in[7];
    const float* bd = (const float*)d_in[8];
    float* out = (float*)d_out;

    char* ws = (char*)d_ws;
    size_t off = 0;
    _Float16* Bp1 = (_Float16*)(ws + off); off += (size_t)K1 * GG * 2;   // 2.36 MB
    _Float16* Bp2 = (_Float16*)(ws + off); off += (size_t)K2 * GG * 2;   // 4.19 MB
    float*    pb1 = (float*)(ws + off);    off += (size_t)GG * 4;
    float*    pb2 = (float*)(ws + off);    off += (size_t)GG * 4;
    _Float16* h1b = (_Float16*)(ws + off); off += (size_t)2 * 2048 * HH * 2; // 4.19 MB
    _Float16* h2b = (_Float16*)(ws + off); off += (size_t)2 * 2048 * HH * 2; // 4.19 MB
    unsigned* bar = (unsigned*)(ws + off); off += 256;

    hipMemsetAsync(h1b, 0, (size_t)2 * 2048 * HH * 2, stream);
    hipMemsetAsync(h2b, 0, (size_t)2 * 2048 * HH * 2, stream);
    hipMemsetAsync(bar, 0, 256, stream);

    pack_weights<<<512, 256, 0, stream>>>(U1, W1, b1, K1, HH, Bp1, pb1);
    pack_weights<<<512, 256, 0, stream>>>(U2, W2, b2, K2, HH, Bp2, pb2);
    lstm_persist<<<NBLK, 512, 0, stream>>>(x, Bp1, pb1, Bp2, pb2, Wd, bd,
                                           h1b, h2b, bar, out);
}